// Round 9
// baseline (34.293 us; speedup 1.0000x reference)
//
#include <hip/hip_runtime.h>

// PyQHamiltonianEvolution: N_QUBITS=20, SUPPORT=(3,8,15), BATCH=8, DIM=8
// state layout (2,)*20 + (8,) row-major, batch innermost.
// element-address support bits: q3 -> bit19 (524288), q8 -> bit14 (16384),
// q15 -> bit7 (128); batch = bits 0-2. Output = f32 REAL part, 2^23 elems.
//
// Kernel A: expm (1 block x 256 thr, f32 scaling-squaring s=5 K=10).
//           Output pair-packed: U4[(i*4+bp)*8+o] = (re[o][2bp], im[o][2bp],
//           re[o][2bp+1], im[o][2bp+1]).
// Kernel B: accumulate-over-i apply. Thread owns a BATCH-PAIR of one rest
//           index: float2 global I/O (24 VMEM instr/thread vs 40 scalar),
//           2048 blocks = 8 blocks/CU, U quads from LDS (bp-stride 9 ->
//           banks {0,4,8,12}, conflict-free broadcast).

#define SUP_OFF(m) ( ((m)&4 ? 524288u : 0u) + ((m)&2 ? 16384u : 0u) + ((m)&1 ? 128u : 0u) )

__global__ void expm_kernel(const float* __restrict__ h_real,
                            const float* __restrict__ h_imag,
                            const float* __restrict__ t_g,
                            float4* __restrict__ U4)   // [(i*4+bp)*8+o] pair-packed
{
    __shared__ float Tre[8][64], Tim[8][64];
    __shared__ float Mre[8][64], Mim[8][64];
    __shared__ float Ere[8][64], Eim[8][64];

    const int tid = threadIdx.x;          // 0..255
    const int b   = tid >> 5;             // batch
    const int e0  = tid & 31;             // entries e0 and e0+32
    const int e1  = e0 + 32;
    const int o0 = e0 >> 3, i0 = e0 & 7;
    const int o1 = e1 >> 3, i1 = e1 & 7;

    const float sc   = t_g[b] * (1.0f / 32.0f);   // M = (-i t H) / 2^5
    const float m0re =  sc * h_imag[e0];
    const float m0im = -sc * h_real[e0];
    const float m1re =  sc * h_imag[e1];
    const float m1im = -sc * h_real[e1];

    Mre[b][e0] = m0re; Mim[b][e0] = m0im;
    Mre[b][e1] = m1re; Mim[b][e1] = m1im;
    Tre[b][e0] = m0re; Tim[b][e0] = m0im;
    Tre[b][e1] = m1re; Tim[b][e1] = m1im;
    float a0re = (o0 == i0 ? 1.f : 0.f) + m0re, a0im = m0im;   // E = I + M
    float a1re = (o1 == i1 ? 1.f : 0.f) + m1re, a1im = m1im;
    __syncthreads();

    for (int k = 2; k <= 10; ++k) {       // T = T*M/k ; E += T
        float s0re = 0.f, s0im = 0.f, s1re = 0.f, s1im = 0.f;
        #pragma unroll
        for (int j = 0; j < 8; ++j) {
            float tre = Tre[b][o0 * 8 + j], tim = Tim[b][o0 * 8 + j];
            float qre = Mre[b][j * 8 + i0], qim = Mim[b][j * 8 + i0];
            s0re += tre * qre - tim * qim;
            s0im += tre * qim + tim * qre;
            tre = Tre[b][o1 * 8 + j]; tim = Tim[b][o1 * 8 + j];
            qre = Mre[b][j * 8 + i1]; qim = Mim[b][j * 8 + i1];
            s1re += tre * qre - tim * qim;
            s1im += tre * qim + tim * qre;
        }
        const float inv = 1.0f / (float)k;
        s0re *= inv; s0im *= inv; s1re *= inv; s1im *= inv;
        __syncthreads();
        Tre[b][e0] = s0re; Tim[b][e0] = s0im;
        Tre[b][e1] = s1re; Tim[b][e1] = s1im;
        a0re += s0re; a0im += s0im;
        a1re += s1re; a1im += s1im;
        __syncthreads();
    }

    Ere[b][e0] = a0re; Eim[b][e0] = a0im;
    Ere[b][e1] = a1re; Eim[b][e1] = a1im;
    __syncthreads();

    for (int sq = 0; sq < 5; ++sq) {      // E = E*E
        float s0re = 0.f, s0im = 0.f, s1re = 0.f, s1im = 0.f;
        #pragma unroll
        for (int j = 0; j < 8; ++j) {
            float xre = Ere[b][o0 * 8 + j], xim = Eim[b][o0 * 8 + j];
            float yre = Ere[b][j * 8 + i0], yim = Eim[b][j * 8 + i0];
            s0re += xre * yre - xim * yim;
            s0im += xre * yim + xim * yre;
            xre = Ere[b][o1 * 8 + j]; xim = Eim[b][o1 * 8 + j];
            yre = Ere[b][j * 8 + i1]; yim = Eim[b][j * 8 + i1];
            s1re += xre * yre - xim * yim;
            s1im += xre * yim + xim * yre;
        }
        __syncthreads();
        Ere[b][e0] = s0re; Eim[b][e0] = s0im;
        Ere[b][e1] = s1re; Eim[b][e1] = s1im;
        __syncthreads();
    }

    // pack: tid = (i*4+bp)*8 + o ; batches (2bp, 2bp+1), entry e = o*8+i
    {
        const int o  = tid & 7;
        const int bp = (tid >> 3) & 3;
        const int i  = tid >> 5;
        const int e  = o * 8 + i;
        const int b0 = 2 * bp, b1 = 2 * bp + 1;
        U4[tid] = make_float4(Ere[b0][e], Eim[b0][e], Ere[b1][e], Eim[b1][e]);
    }
}

__global__ __launch_bounds__(256, 8) void apply_kernel(
        const float* __restrict__ sre_g,
        const float* __restrict__ sim_g,
        const float4* __restrict__ U4,   // 256 pair-packed quads
        float* __restrict__ out)
{
    // LDS: slot (i*4+bp), stride 9 float4s -> read banks {0,4,8,12}+base,
    // conflict-free 4-address broadcast.
    __shared__ alignas(16) float4 uL[8 * 4 * 9];
    const int tid = threadIdx.x;
    {
        const int ib = tid >> 3, o = tid & 7;
        uL[ib * 9 + o] = U4[tid];
    }
    __syncthreads();

    const unsigned t   = blockIdx.x * 256u + tid;   // [0, 2^19)
    const unsigned rho = t >> 2;                    // rest index [0, 2^17)
    const int      bp  = t & 3;                     // batch pair

    // spread rho's 17 bits into octet bits, skipping oct bits 4, 11, 16
    const unsigned oct = (rho & 0xFu)
                       | ((rho & 0x3F0u)   << 1)
                       | ((rho & 0x3C00u)  << 2)
                       | ((rho & 0x1C000u) << 3);
    const unsigned base = (oct << 3) + 2u * bp;     // element address

    float2 acc[8];
    #pragma unroll
    for (int o = 0; o < 8; ++o) acc[o] = make_float2(0.f, 0.f);

    // i-pairs: issue 4 float2 loads, then consume (compiler hoists further)
    #pragma unroll
    for (int ip = 0; ip < 4; ++ip) {
        const int ia = 2 * ip, ib2 = 2 * ip + 1;
        const unsigned offa = base + SUP_OFF(ia);
        const unsigned offb = base + SUP_OFF(ib2);

        const float2 xra = *(const float2*)(sre_g + offa);
        const float2 xia = *(const float2*)(sim_g + offa);
        const float2 xrb = *(const float2*)(sre_g + offb);
        const float2 xib = *(const float2*)(sim_g + offb);

        const float4* uqa = &uL[(ia  * 4 + bp) * 9];
        const float4* uqb = &uL[(ib2 * 4 + bp) * 9];
        #pragma unroll
        for (int o = 0; o < 8; ++o) {
            const float4 qa = uqa[o];   // (re_b0, im_b0, re_b1, im_b1)
            acc[o].x += qa.x * xra.x - qa.y * xia.x;
            acc[o].y += qa.z * xra.y - qa.w * xia.y;
        }
        #pragma unroll
        for (int o = 0; o < 8; ++o) {
            const float4 qb = uqb[o];
            acc[o].x += qb.x * xrb.x - qb.y * xib.x;
            acc[o].y += qb.z * xrb.y - qb.w * xib.y;
        }
    }

    #pragma unroll
    for (int o = 0; o < 8; ++o) {
        *(float2*)(out + base + SUP_OFF(o)) = acc[o];
    }
}

extern "C" void kernel_launch(void* const* d_in, const int* in_sizes, int n_in,
                              void* d_out, int out_size, void* d_ws, size_t ws_size,
                              hipStream_t stream) {
    const float* state_real = (const float*)d_in[0];
    const float* state_imag = (const float*)d_in[1];
    const float* h_real     = (const float*)d_in[2];
    const float* h_imag     = (const float*)d_in[3];
    const float* t          = (const float*)d_in[4];

    float4* U4 = (float4*)d_ws;   // 256 float4 = 4 KB

    expm_kernel<<<1, 256, 0, stream>>>(h_real, h_imag, t, U4);

    // 2^19 batch-pair threads / 256 = 2048 blocks (8 blocks/CU)
    apply_kernel<<<2048, 256, 0, stream>>>(state_real, state_imag, U4,
                                           (float*)d_out);
}

// Round 10
// 26.960 us; speedup vs baseline: 1.2720x; 1.2720x over previous
//
#include <hip/hip_runtime.h>

// PyQHamiltonianEvolution: N_QUBITS=20, SUPPORT=(3,8,15), BATCH=8, DIM=8
// state layout (2,)*20 + (8,) row-major, batch innermost.
// element-address support bits: q3 -> bit19 (524288), q8 -> bit14 (16384),
// q15 -> bit7 (128); batch = bits 0-2. Output = f32 REAL part, 2^23 elems.
//
// Kernel A: expm, 8 blocks x 64 threads (one wave per batch; barriers ~free).
//           U stored to d_ws as float[1024]: [(i*8+b)*16 + 2o] = re, +1 = im.
// Kernel B: R8 structure + FULL LOAD HOIST: thread owns 2 elements
//           (r, r+256); ALL 32 x-loads issued up front (max MLP), then
//           accumulate-over-i from registers with U columns from LDS
//           (stride-20 pad, conflict-free broadcast). 2048 blocks = 8/CU.

#define SUP_OFF(m) ( ((m)&4 ? 524288u : 0u) + ((m)&2 ? 16384u : 0u) + ((m)&1 ? 128u : 0u) )

__global__ void expm_kernel(const float* __restrict__ h_real,
                            const float* __restrict__ h_imag,
                            const float* __restrict__ t_g,
                            float* __restrict__ U)     // [ (i*8+b)*16 + 2o (+1) ]
{
    __shared__ float Tre[64], Tim[64], Mre[64], Mim[64], Ere[64], Eim[64];

    const int b = blockIdx.x;          // batch
    const int e = threadIdx.x;         // matrix entry, one per lane
    const int o = e >> 3, i = e & 7;

    const float sc  = t_g[b] * (1.0f / 32.0f);   // M = (-i t H) / 2^5
    const float mre =  sc * h_imag[e];
    const float mim = -sc * h_real[e];

    Mre[e] = mre; Mim[e] = mim;
    Tre[e] = mre; Tim[e] = mim;
    float are = (o == i ? 1.f : 0.f) + mre;      // E = I + M
    float aim = mim;
    __syncthreads();

    for (int k = 2; k <= 10; ++k) {    // T = T*M/k ; E += T
        float sre = 0.f, sim = 0.f;
        #pragma unroll
        for (int j = 0; j < 8; ++j) {
            const float tre = Tre[o * 8 + j], tim = Tim[o * 8 + j];
            const float qre = Mre[j * 8 + i], qim = Mim[j * 8 + i];
            sre += tre * qre - tim * qim;
            sim += tre * qim + tim * qre;
        }
        const float inv = 1.0f / (float)k;
        sre *= inv; sim *= inv;
        __syncthreads();
        Tre[e] = sre; Tim[e] = sim;
        are += sre; aim += sim;
        __syncthreads();
    }

    Ere[e] = are; Eim[e] = aim;
    __syncthreads();

    for (int sq = 0; sq < 5; ++sq) {   // E = E*E
        float sre = 0.f, sim = 0.f;
        #pragma unroll
        for (int j = 0; j < 8; ++j) {
            const float xre = Ere[o * 8 + j], xim = Eim[o * 8 + j];
            const float yre = Ere[j * 8 + i], yim = Eim[j * 8 + i];
            sre += xre * yre - xim * yim;
            sim += xre * yim + xim * yre;
        }
        __syncthreads();
        if (sq < 4) {
            Ere[e] = sre; Eim[e] = sim;
            __syncthreads();
        } else {
            U[(i * 8 + b) * 16 + 2 * o]     = sre;   // column-major for apply
            U[(i * 8 + b) * 16 + 2 * o + 1] = sim;
        }
    }
}

__global__ __launch_bounds__(256, 8) void apply_kernel(
        const float* __restrict__ sre_g,
        const float* __restrict__ sim_g,
        const float4* __restrict__ U4,   // 256 float4 = [i][b][16 floats]
        float* __restrict__ out)
{
    // LDS: [i][b] slots, stride 20 floats (banks b*20 mod 32 all distinct ->
    // conflict-free 8-address broadcast reads, 16B-aligned).
    __shared__ alignas(16) float uL[8 * 8 * 20];
    const int tid = threadIdx.x;
    {
        const float4 u = U4[tid];            // tid = (i*8+b)*4 + k
        const int ib = tid >> 2, k = tid & 3;
        *(float4*)&uL[ib * 20 + k * 4] = u;
    }
    __syncthreads();

    const unsigned rbase = blockIdx.x * 512u + tid;   // block owns 512 r
    const int b = tid & 7;                            // same b for both sets

    unsigned addr[2];
    #pragma unroll
    for (int s = 0; s < 2; ++s) {
        const unsigned r = rbase + 256u * s;
        addr[s] = (r & 0x7Fu)
                | ((r & 0x1F80u)  << 1)
                | ((r & 0x1E000u) << 2)
                | ((r & 0xE0000u) << 3);
    }

    // ---- FULL HOIST: issue all 32 independent loads before any consumption.
    float xr[2][8], xi[2][8];
    #pragma unroll
    for (int i = 0; i < 8; ++i) {
        const unsigned so = SUP_OFF(i);
        xr[0][i] = sre_g[addr[0] + so];
        xr[1][i] = sre_g[addr[1] + so];
        xi[0][i] = sim_g[addr[0] + so];
        xi[1][i] = sim_g[addr[1] + so];
    }

    float acc[2][8];
    #pragma unroll
    for (int s = 0; s < 2; ++s)
        #pragma unroll
        for (int o = 0; o < 8; ++o) acc[s][o] = 0.f;

    // ---- consume from registers; U columns from LDS (broadcast reads).
    #pragma unroll
    for (int i = 0; i < 8; ++i) {
        const float4* uv = (const float4*)&uL[(i * 8 + b) * 20];
        const float4 u01 = uv[0], u23 = uv[1], u45 = uv[2], u67 = uv[3];
        const float xr0 = xr[0][i], xi0 = xi[0][i];
        const float xr1 = xr[1][i], xi1 = xi[1][i];
        acc[0][0] += u01.x * xr0 - u01.y * xi0;
        acc[0][1] += u01.z * xr0 - u01.w * xi0;
        acc[0][2] += u23.x * xr0 - u23.y * xi0;
        acc[0][3] += u23.z * xr0 - u23.w * xi0;
        acc[0][4] += u45.x * xr0 - u45.y * xi0;
        acc[0][5] += u45.z * xr0 - u45.w * xi0;
        acc[0][6] += u67.x * xr0 - u67.y * xi0;
        acc[0][7] += u67.z * xr0 - u67.w * xi0;
        acc[1][0] += u01.x * xr1 - u01.y * xi1;
        acc[1][1] += u01.z * xr1 - u01.w * xi1;
        acc[1][2] += u23.x * xr1 - u23.y * xi1;
        acc[1][3] += u23.z * xr1 - u23.w * xi1;
        acc[1][4] += u45.x * xr1 - u45.y * xi1;
        acc[1][5] += u45.z * xr1 - u45.w * xi1;
        acc[1][6] += u67.x * xr1 - u67.y * xi1;
        acc[1][7] += u67.z * xr1 - u67.w * xi1;
    }

    #pragma unroll
    for (int o = 0; o < 8; ++o) {
        const unsigned so = SUP_OFF(o);
        out[addr[0] + so] = acc[0][o];
        out[addr[1] + so] = acc[1][o];
    }
}

extern "C" void kernel_launch(void* const* d_in, const int* in_sizes, int n_in,
                              void* d_out, int out_size, void* d_ws, size_t ws_size,
                              hipStream_t stream) {
    const float* state_real = (const float*)d_in[0];
    const float* state_imag = (const float*)d_in[1];
    const float* h_real     = (const float*)d_in[2];
    const float* h_imag     = (const float*)d_in[3];
    const float* t          = (const float*)d_in[4];

    float* U = (float*)d_ws;   // 1024 floats = 4 KB

    expm_kernel<<<8, 64, 0, stream>>>(h_real, h_imag, t, U);

    // 2^20 elements / 2 per thread / 256 per block = 2048 blocks (8/CU)
    apply_kernel<<<2048, 256, 0, stream>>>(state_real, state_imag,
                                           (const float4*)U, (float*)d_out);
}

// Round 11
// 26.266 us; speedup vs baseline: 1.3056x; 1.0264x over previous
//
#include <hip/hip_runtime.h>

// PyQHamiltonianEvolution: N_QUBITS=20, SUPPORT=(3,8,15), BATCH=8, DIM=8
// state layout (2,)*20 + (8,) row-major, batch innermost.
// element-address support bits: q3 -> bit19 (524288), q8 -> bit14 (16384),
// q15 -> bit7 (128); batch = bits 0-2. Output = f32 REAL part, 2^23 elems.
//
// Round 11: FULL-CONTIGUITY restructure. All global I/O is contiguous 2KB
// runs; the support-bit gather/scatter happens in LDS.
//   tile = addr bits 0-8 (512 contiguous elems, contains support bit 7)
//          x 4 far combos c=(q3,q8) (bits 19,14)  -> 2048 elements.
//   stage: 4 chunks x 2KB x 2 planes in (float2/lane, contiguous)
//   compute: thread owns (l, rb); reads its 8 combos from LDS (stride-1 per
//            instr, conflict-free); U columns via R8's stride-20 broadcast.
//   out: 8 results staged into the consumed re-plane buffer, then 4 chunks
//        x 2KB contiguous float2 stores.
// Kernel A (expm) unchanged: 8 blocks x 64 thr, f32 scaling-squaring.

#define SUP_OFF(m) ( ((m)&4 ? 524288u : 0u) + ((m)&2 ? 16384u : 0u) + ((m)&1 ? 128u : 0u) )

__global__ void expm_kernel(const float* __restrict__ h_real,
                            const float* __restrict__ h_imag,
                            const float* __restrict__ t_g,
                            float* __restrict__ U)     // [ (i*8+b)*16 + 2o (+1) ]
{
    __shared__ float Tre[64], Tim[64], Mre[64], Mim[64], Ere[64], Eim[64];

    const int b = blockIdx.x;          // batch
    const int e = threadIdx.x;         // matrix entry, one per lane
    const int o = e >> 3, i = e & 7;

    const float sc  = t_g[b] * (1.0f / 32.0f);   // M = (-i t H) / 2^5
    const float mre =  sc * h_imag[e];
    const float mim = -sc * h_real[e];

    Mre[e] = mre; Mim[e] = mim;
    Tre[e] = mre; Tim[e] = mim;
    float are = (o == i ? 1.f : 0.f) + mre;      // E = I + M
    float aim = mim;
    __syncthreads();

    for (int k = 2; k <= 10; ++k) {    // T = T*M/k ; E += T
        float sre = 0.f, sim = 0.f;
        #pragma unroll
        for (int j = 0; j < 8; ++j) {
            const float tre = Tre[o * 8 + j], tim = Tim[o * 8 + j];
            const float qre = Mre[j * 8 + i], qim = Mim[j * 8 + i];
            sre += tre * qre - tim * qim;
            sim += tre * qim + tim * qre;
        }
        const float inv = 1.0f / (float)k;
        sre *= inv; sim *= inv;
        __syncthreads();
        Tre[e] = sre; Tim[e] = sim;
        are += sre; aim += sim;
        __syncthreads();
    }

    Ere[e] = are; Eim[e] = aim;
    __syncthreads();

    for (int sq = 0; sq < 5; ++sq) {   // E = E*E
        float sre = 0.f, sim = 0.f;
        #pragma unroll
        for (int j = 0; j < 8; ++j) {
            const float xre = Ere[o * 8 + j], xim = Eim[o * 8 + j];
            const float yre = Ere[j * 8 + i], yim = Eim[j * 8 + i];
            sre += xre * yre - xim * yim;
            sim += xre * yim + xim * yre;
        }
        __syncthreads();
        if (sq < 4) {
            Ere[e] = sre; Eim[e] = sim;
            __syncthreads();
        } else {
            U[(i * 8 + b) * 16 + 2 * o]     = sre;   // column-major for apply
            U[(i * 8 + b) * 16 + 2 * o + 1] = sim;
        }
    }
}

__global__ __launch_bounds__(256, 7) void apply_kernel(
        const float* __restrict__ sre_g,
        const float* __restrict__ sim_g,
        const float4* __restrict__ U4,   // 256 float4 = [i][b][16 floats]
        float* __restrict__ out)
{
    // x planes: [c][rb][s15][l] = [4][2][2][128] floats = 2048 each.
    __shared__ alignas(16) float ldsRe[2048];
    __shared__ alignas(16) float ldsIm[2048];
    // U: [i][b] slots, stride 20 floats (banks b*20 mod 32 all distinct ->
    // conflict-free 8-address broadcast reads, 16B-aligned).
    __shared__ alignas(16) float uL[8 * 8 * 20];

    const int tid = threadIdx.x;

    // ---- stage U + 4 contiguous 2KB chunks per plane (all loads up front)
    {
        const float4 u = U4[tid];            // tid = (i*8+b)*4 + k
        const int ib = tid >> 2, k = tid & 3;
        *(float4*)&uL[ib * 20 + k * 4] = u;
    }

    const unsigned B = blockIdx.x;           // 12 bits
    // block bits -> addr bits 9-13, 15-18, 20-22
    const unsigned addr_hi = ((B & 0x1Fu)  << 9)
                           | ((B & 0x1E0u) << 10)
                           | ((B & 0xE00u) << 11);

    #pragma unroll
    for (int c = 0; c < 4; ++c) {            // c = (q3<<1)|q8
        const unsigned gbase = addr_hi + ((c & 2) ? 524288u : 0u)
                                       + ((c & 1) ? 16384u  : 0u);
        *(float2*)&ldsRe[c * 512 + tid * 2] = *(const float2*)(sre_g + gbase + tid * 2);
        *(float2*)&ldsIm[c * 512 + tid * 2] = *(const float2*)(sim_g + gbase + tid * 2);
    }
    __syncthreads();

    // ---- compute: thread owns (l = tid&127, rb = tid>>7); batch b = l&7
    const int l  = tid & 127;
    const int rb = tid >> 7;
    const int b  = l & 7;
    const int xbase = rb * 256 + l;          // + c*512 + s15*128

    float acc[8];
    #pragma unroll
    for (int o = 0; o < 8; ++o) acc[o] = 0.f;

    #pragma unroll
    for (int i = 0; i < 8; ++i) {            // i = (q3<<2)|(q8<<1)|q15
        const int xoff = (i >> 1) * 512 + (i & 1) * 128 + xbase;
        const float xr = ldsRe[xoff];
        const float xi = ldsIm[xoff];
        const float4* uv = (const float4*)&uL[(i * 8 + b) * 20];
        const float4 u01 = uv[0], u23 = uv[1], u45 = uv[2], u67 = uv[3];
        acc[0] += u01.x * xr - u01.y * xi;
        acc[1] += u01.z * xr - u01.w * xi;
        acc[2] += u23.x * xr - u23.y * xi;
        acc[3] += u23.z * xr - u23.w * xi;
        acc[4] += u45.x * xr - u45.y * xi;
        acc[5] += u45.z * xr - u45.w * xi;
        acc[6] += u67.x * xr - u67.y * xi;
        acc[7] += u67.z * xr - u67.w * xi;
    }
    __syncthreads();                         // re/im planes fully consumed

    // ---- scatter outputs into (reused) re-plane buffer
    #pragma unroll
    for (int o = 0; o < 8; ++o) {
        ldsRe[(o >> 1) * 512 + (o & 1) * 128 + xbase] = acc[o];
    }
    __syncthreads();

    // ---- contiguous 2KB stores
    #pragma unroll
    for (int c = 0; c < 4; ++c) {
        const unsigned gbase = addr_hi + ((c & 2) ? 524288u : 0u)
                                       + ((c & 1) ? 16384u  : 0u);
        *(float2*)(out + gbase + tid * 2) = *(const float2*)&ldsRe[c * 512 + tid * 2];
    }
}

extern "C" void kernel_launch(void* const* d_in, const int* in_sizes, int n_in,
                              void* d_out, int out_size, void* d_ws, size_t ws_size,
                              hipStream_t stream) {
    const float* state_real = (const float*)d_in[0];
    const float* state_imag = (const float*)d_in[1];
    const float* h_real     = (const float*)d_in[2];
    const float* h_imag     = (const float*)d_in[3];
    const float* t          = (const float*)d_in[4];

    float* U = (float*)d_ws;   // 1024 floats = 4 KB

    expm_kernel<<<8, 64, 0, stream>>>(h_real, h_imag, t, U);

    // 2^23 elements / 2048 per block = 4096 blocks
    apply_kernel<<<4096, 256, 0, stream>>>(state_real, state_imag,
                                           (const float4*)U, (float*)d_out);
}